// Round 2
// baseline (478.415 us; speedup 1.0000x reference)
//
#include <hip/hip_runtime.h>
#include <cstdint>
#include <cstddef>

#define BB 64
#define NN 1024
#define DD 128

typedef short    bf16x8 __attribute__((ext_vector_type(8)));
typedef _Float16 f16x8  __attribute__((ext_vector_type(8)));
typedef float    f32x4  __attribute__((ext_vector_type(4)));

__device__ __forceinline__ unsigned short f2bf(float f) {
  union { float f; unsigned u; } v; v.f = f;
  unsigned r = v.u + 0x7FFFu + ((v.u >> 16) & 1u);
  return (unsigned short)(r >> 16);
}
__device__ __forceinline__ unsigned short f2h(float f) {
  union { _Float16 h; unsigned short u; } v; v.h = (_Float16)f;
  return v.u;
}
__device__ __forceinline__ float fast_tanh(float x) {
  x = fminf(15.0f, fmaxf(-15.0f, x));
  float e = __expf(2.0f * x);
  return (e - 1.0f) / (e + 1.0f);
}

// async global->LDS DMA, 16 B per lane (global_load_lds_dwordx4)
__device__ __forceinline__ void async_copy16(void* lptr, const void* gptr) {
  __builtin_amdgcn_global_load_lds(
      (const __attribute__((address_space(1))) unsigned int*)gptr,
      (__attribute__((address_space(3))) unsigned int*)lptr, 16, 0, 0);
}

// pack 16 mask ints (one 64-col tile slice for this lane) into 16 bits:
// bit (i*4 + {0,1,2,3}) = m[i].{x,y,z,w} & 1. Consumption at PV:
// bit (ks2*8+e) gates column j0 + ks2*32 + quad*8 + e.
__device__ __forceinline__ unsigned pack_mask(const int4 m[4]) {
  unsigned mb = 0;
#pragma unroll
  for (int i = 0; i < 4; ++i) {
    mb |= (unsigned)(m[i].x & 1) << (i * 4 + 0);
    mb |= (unsigned)(m[i].y & 1) << (i * 4 + 1);
    mb |= (unsigned)(m[i].z & 1) << (i * 4 + 2);
    mb |= (unsigned)(m[i].w & 1) << (i * 4 + 3);
  }
  return mb;
}

// ---------------------------------------------------------------------------
// Kernel 1: q = tanh(x@Wq^T+bq) (fp16), k = tanh(x@Wk^T+bk) (fp16),
//           vT = tanh(x@Wv^T+bv) transposed (bf16, [b][h][n]).  (unchanged)
// ---------------------------------------------------------------------------
__global__ __launch_bounds__(256, 2) void proj_kernel(
    const float* __restrict__ x,
    const float* __restrict__ Wq, const float* __restrict__ bq,
    const float* __restrict__ Wk, const float* __restrict__ bk,
    const float* __restrict__ Wv, const float* __restrict__ bv,
    unsigned short* __restrict__ qg,   // fp16 [B][N][D]
    unsigned short* __restrict__ kg,   // fp16 [B][N][D]
    unsigned short* __restrict__ vtg)  // bf16 [B][D][N]
{
  __shared__ unsigned short wlds[128 * 136];

  const int tid  = threadIdx.x;
  const int lane = tid & 63;
  const int wave = tid >> 6;
  const int quad = lane >> 4;
  const int mr   = lane & 15;
  const int m0   = blockIdx.x * 128;
  const int batch = m0 >> 10;
  const int n0    = m0 & 1023;

  bf16x8 xa[2][4];
#pragma unroll
  for (int mt = 0; mt < 2; ++mt) {
    const float* xr = x + (size_t)(m0 + wave * 32 + mt * 16 + mr) * DD + quad * 8;
#pragma unroll
    for (int ks = 0; ks < 4; ++ks) {
      const float4* xp = (const float4*)(xr + ks * 32);
      float4 f0 = xp[0], f1 = xp[1];
      bf16x8 f;
      f[0] = (short)f2bf(f0.x); f[1] = (short)f2bf(f0.y);
      f[2] = (short)f2bf(f0.z); f[3] = (short)f2bf(f0.w);
      f[4] = (short)f2bf(f1.x); f[5] = (short)f2bf(f1.y);
      f[6] = (short)f2bf(f1.z); f[7] = (short)f2bf(f1.w);
      xa[mt][ks] = f;
    }
  }

  const float* Wp[3] = {Wq, Wk, Wv};
  const float* bp[3] = {bq, bk, bv};

  for (int w = 0; w < 3; ++w) {
    __syncthreads();
    {
      const int row = tid >> 1, half = tid & 1;
      const float* src = Wp[w] + row * 128 + half * 64;
      unsigned short* dst = wlds + row * 136 + half * 64;
#pragma unroll
      for (int c = 0; c < 64; c += 8) {
        const float4* sp = (const float4*)(src + c);
        float4 f0 = sp[0], f1 = sp[1];
        unsigned short tmp[8];
        tmp[0] = f2bf(f0.x); tmp[1] = f2bf(f0.y); tmp[2] = f2bf(f0.z); tmp[3] = f2bf(f0.w);
        tmp[4] = f2bf(f1.x); tmp[5] = f2bf(f1.y); tmp[6] = f2bf(f1.z); tmp[7] = f2bf(f1.w);
        uint4 pk; __builtin_memcpy(&pk, tmp, 16);
        *(uint4*)(dst + c) = pk;
      }
    }
    __syncthreads();

    f32x4 z = {0.f, 0.f, 0.f, 0.f};
    f32x4 acc[2][8];
#pragma unroll
    for (int mt = 0; mt < 2; ++mt)
#pragma unroll
      for (int nt = 0; nt < 8; ++nt) acc[mt][nt] = z;

#pragma unroll
    for (int ks = 0; ks < 4; ++ks) {
#pragma unroll
      for (int nt = 0; nt < 8; ++nt) {
        bf16x8 bfr = *(const bf16x8*)(wlds + (nt * 16 + mr) * 136 + ks * 32 + quad * 8);
        acc[0][nt] = __builtin_amdgcn_mfma_f32_16x16x32_bf16(xa[0][ks], bfr, acc[0][nt], 0, 0, 0);
        acc[1][nt] = __builtin_amdgcn_mfma_f32_16x16x32_bf16(xa[1][ks], bfr, acc[1][nt], 0, 0, 0);
      }
    }

    if (w < 2) {
      unsigned short* outg = (w == 0) ? qg : kg;
#pragma unroll
      for (int mt = 0; mt < 2; ++mt) {
        const int rowbase = m0 + wave * 32 + mt * 16 + quad * 4;
#pragma unroll
        for (int nt = 0; nt < 8; ++nt) {
          float bb = bp[w][nt * 16 + mr];
#pragma unroll
          for (int r = 0; r < 4; ++r) {
            float t = fast_tanh(acc[mt][nt][r] + bb);
            outg[(size_t)(rowbase + r) * DD + nt * 16 + mr] = f2h(t);
          }
        }
      }
    } else {
      __syncthreads();
#pragma unroll
      for (int mt = 0; mt < 2; ++mt) {
        const int ib = wave * 32 + mt * 16 + quad * 4;
#pragma unroll
        for (int nt = 0; nt < 8; ++nt) {
          float bb = bp[2][nt * 16 + mr];
#pragma unroll
          for (int r = 0; r < 4; ++r) {
            float t = fast_tanh(acc[mt][nt][r] + bb);
            wlds[(nt * 16 + mr) * 136 + ib + r] = f2bf(t);
          }
        }
      }
      __syncthreads();
      const int h = tid >> 1, half = tid & 1;
      const unsigned short* src = wlds + h * 136 + half * 64;
      unsigned short* dst = vtg + (size_t)(batch * 128 + h) * NN + n0 + half * 64;
#pragma unroll
      for (int c = 0; c < 64; c += 8)
        *(uint4*)(dst + c) = *(const uint4*)(src + c);
    }
  }
}

// ---------------------------------------------------------------------------
// Kernel 2: flash-style masked attention, R2: 2-phase double-buffered DMA.
// Block = 64 q-rows (4 waves x 16 rows), j-tiles of 64.
//
// Pipeline (T3-minimum, guide §5.5): K/VT double-buffered (2 x 32 KB = 64 KB
// LDS, 2 blocks/CU). stage(t+1) -> buf[cur^1] issued BEFORE computing tile t;
// drained at next loop-top __syncthreads (vmcnt(0)) -- a full S+exp+PV phase
// (~1000 cyc) separates issue from drain, vs the previous issue->drain-now
// structure that exposed full HBM/L2 latency every tile.
//   - mask loads issued BEFORE the stage DMAs: pack_mask's compiler waitcnt
//     becomes counted vmcnt(16) (vmcnt is FIFO) instead of draining the DMA.
//   - mid-tile B3 is lgkm-ONLY (raw s_barrier): __syncthreads there would
//     emit vmcnt(0) and kill the pipeline.
//   - rowsum via MFMA vs ones-B-frag: rs=mfma(pm,ones,rs). D-layout rows
//     (quad*4+r, col=mr) match o[nt][r] exactly -> no cross-quad shuffles,
//     -32 VALU/tile/lane.
// LDS per buffer: K [64][128] f16 XOR-swizzled (8192 sh), VT [128][64] bf16
// XOR-swizzled (8192 sh). plds [64][72] aliases current klds after B3.
// ---------------------------------------------------------------------------
__global__ __launch_bounds__(256, 2) void attn_kernel(
    const unsigned short* __restrict__ qg,
    const unsigned short* __restrict__ kg,
    const unsigned short* __restrict__ vtg,
    const int* __restrict__ mask,
    float* __restrict__ out)
{
  extern __shared__ unsigned short lds[];  // [2][ K:8192 | VT:8192 ] shorts = 64 KB

  const int tid  = threadIdx.x;
  const int lane = tid & 63;
  const int wave = tid >> 6;
  const int quad = lane >> 4;
  const int mr   = lane & 15;

  const int bx    = blockIdx.x;
  const int batch = ((bx >> 7) << 3) | (bx & 7);   // same-batch blocks -> same XCD
  const int i0    = ((bx >> 3) & 15) * 64;

  const unsigned short* kgb = kg  + (size_t)batch * NN * DD;
  const unsigned short* vtb = vtg + (size_t)batch * DD * NN;
  const int* mrow = mask + ((size_t)batch << 20) + (size_t)(i0 + wave * 16 + mr) * NN;

  // Q A-frags (fp16): row = i0 + wave*16 + mr, k = ks*32 + quad*8 + e
  f16x8 qa[4];
#pragma unroll
  for (int ks = 0; ks < 4; ++ks)
    qa[ks] = *(const f16x8*)(qg +
        ((size_t)batch * NN + i0 + wave * 16 + mr) * DD + ks * 32 + quad * 8);

  f32x4 z = {0.f, 0.f, 0.f, 0.f};
  f32x4 o[8];
#pragma unroll
  for (int nt = 0; nt < 8; ++nt) o[nt] = z;
  f32x4 rs = z;                       // rowsum accumulator (MFMA vs ones)
  bf16x8 ones;
#pragma unroll
  for (int e = 0; e < 8; ++e) ones[e] = (short)0x3F80;  // bf16 1.0

  // mask tile 0 loads FIRST (so the pack below doesn't drain the stage DMA)
  int4 mreg0[4];
  mreg0[0] = *(const int4*)(mrow + quad * 8);
  mreg0[1] = *(const int4*)(mrow + quad * 8 + 4);
  mreg0[2] = *(const int4*)(mrow + 32 + quad * 8);
  mreg0[3] = *(const int4*)(mrow + 32 + quad * 8 + 4);

  // prologue: stage tile 0 into buffer 0
  {
    unsigned short* klds0 = lds;
    unsigned short* vlds0 = lds + 8192;
#pragma unroll
    for (int p = 0; p < 4; ++p) {
      int s = p * 256 + tid;
      int kr = s >> 4, kgp = (s & 15) ^ (kr & 15);
      async_copy16(klds0 + s * 8, kgb + (size_t)kr * DD + kgp * 8);
    }
#pragma unroll
    for (int p = 0; p < 4; ++p) {
      int s = p * 256 + tid;
      int vr = s >> 3, vgp = (s & 7) ^ (vr & 7);
      async_copy16(vlds0 + s * 8, vtb + (size_t)vr * NN + vgp * 8);
    }
  }

  unsigned mb = pack_mask(mreg0);

  int cur = 0;
  for (int t = 0; t < 16; ++t) {
    unsigned short* klds_c = lds + cur * 16384;
    unsigned short* vlds_c = lds + cur * 16384 + 8192;
    unsigned short* plds_c = klds_c;               // alias, valid after B3

    __syncthreads();  // LOOP-TOP: vmcnt(0)+barrier -> tile t staging visible;
                      // all waves done reading buf[cur^1] (prev tile's PV)

    // mask loads for tile t+1 (before stage DMA -- see header comment)
    int4 mreg[4];
    {
      const int j0n = ((t + 1) & 15) * 64;
      mreg[0] = *(const int4*)(mrow + j0n + quad * 8);
      mreg[1] = *(const int4*)(mrow + j0n + quad * 8 + 4);
      mreg[2] = *(const int4*)(mrow + j0n + 32 + quad * 8);
      mreg[3] = *(const int4*)(mrow + j0n + 32 + quad * 8 + 4);
    }

    // stage tile t+1 into buf[cur^1]; stays in flight until next loop-top
    if (t < 15) {
      unsigned short* klds_n = lds + (cur ^ 1) * 16384;
      unsigned short* vlds_n = lds + (cur ^ 1) * 16384 + 8192;
      const int j0s = (t + 1) * 64;
#pragma unroll
      for (int p = 0; p < 4; ++p) {
        int s = p * 256 + tid;
        int kr = s >> 4, kgp = (s & 15) ^ (kr & 15);
        async_copy16(klds_n + s * 8, kgb + (size_t)(j0s + kr) * DD + kgp * 8);
      }
#pragma unroll
      for (int p = 0; p < 4; ++p) {
        int s = p * 256 + tid;
        int vr = s >> 3, vgp = (s & 7) ^ (vr & 7);
        async_copy16(vlds_n + s * 8, vtb + (size_t)vr * NN + j0s + vgp * 8);
      }
    }

    // S = Q @ K^T (fp16 MFMA); per-wave tile 16 x 64; swizzled klds reads
    f32x4 s[4];
#pragma unroll
    for (int nt = 0; nt < 4; ++nt) s[nt] = z;
    __builtin_amdgcn_s_setprio(1);
#pragma unroll
    for (int ks = 0; ks < 4; ++ks) {
#pragma unroll
      for (int nt = 0; nt < 4; ++nt) {
        f16x8 kb = *(const f16x8*)(klds_c + (nt * 16 + mr) * 128 + (((ks * 4 + quad) ^ mr) * 8));
        s[nt] = __builtin_amdgcn_mfma_f32_16x16x32_f16(qa[ks], kb, s[nt], 0, 0, 0);
      }
    }
    __builtin_amdgcn_s_setprio(0);

    // pack next tile's mask (counted vmcnt wait; DMA stays outstanding)
    unsigned mb_next = pack_mask(mreg);

    // B3: klds_c reads done -> region becomes plds. LGKM-ONLY barrier:
    // a __syncthreads here would drain vmcnt(0) and serialize the DMA.
    asm volatile("s_waitcnt lgkmcnt(0)" ::: "memory");
    __builtin_amdgcn_s_barrier();

    // P = exp(S) -> bf16 -> plds (unmasked; mask applied at A-frag read).
    // P rows are wave-private; same-wave ds_write->ds_read via lgkmcnt.
#pragma unroll
    for (int nt = 0; nt < 4; ++nt) {
#pragma unroll
      for (int r = 0; r < 4; ++r)
        plds_c[(wave * 16 + quad * 4 + r) * 72 + nt * 16 + mr] = f2bf(__expf(s[nt][r]));
    }

    // O += P_masked @ V; rowsum via MFMA against ones-B-frag
#pragma unroll
    for (int ks2 = 0; ks2 < 2; ++ks2) {
      bf16x8 pa = *(const bf16x8*)(plds_c + (wave * 16 + mr) * 72 + ks2 * 32 + quad * 8);
      bf16x8 pm;
#pragma unroll
      for (int e = 0; e < 8; ++e) {
        unsigned bit = (mb >> (ks2 * 8 + e)) & 1u;
        pm[e] = bit ? pa[e] : (short)0;
      }
      rs = __builtin_amdgcn_mfma_f32_16x16x32_bf16(pm, ones, rs, 0, 0, 0);
      __builtin_amdgcn_s_setprio(1);
#pragma unroll
      for (int nt = 0; nt < 8; ++nt) {
        bf16x8 vb = *(const bf16x8*)(vlds_c + (nt * 16 + mr) * 64 +
                                     (((ks2 * 4 + quad) ^ (mr & 7)) * 8));
        o[nt] = __builtin_amdgcn_mfma_f32_16x16x32_bf16(pm, vb, o[nt], 0, 0, 0);
      }
      __builtin_amdgcn_s_setprio(0);
    }

    mb = mb_next;
    cur ^= 1;
  }

  // rs[r] holds the full masked rowsum for row wave*16+quad*4+r (col=mr,
  // value col-independent) -- same lane mapping as o[nt][r]: no shuffles.
  float* ob = out + ((size_t)batch * NN + i0) * DD;
#pragma unroll
  for (int r = 0; r < 4; ++r) {
    float inv = 1.0f / rs[r];
    float* orow = ob + (size_t)(wave * 16 + quad * 4 + r) * DD + mr;
#pragma unroll
    for (int nt = 0; nt < 8; ++nt)
      orow[nt * 16] = o[nt][r] * inv;
  }
}

// ---------------------------------------------------------------------------
extern "C" void kernel_launch(void* const* d_in, const int* in_sizes, int n_in,
                              void* d_out, int out_size, void* d_ws, size_t ws_size,
                              hipStream_t stream) {
  (void)in_sizes; (void)n_in; (void)out_size; (void)ws_size;
  const float* x  = (const float*)d_in[0];
  const int* mask = (const int*)d_in[1];
  const float* Wv = (const float*)d_in[2];
  const float* bv = (const float*)d_in[3];
  const float* Wk = (const float*)d_in[4];
  const float* bk = (const float*)d_in[5];
  const float* Wq = (const float*)d_in[6];
  const float* bq = (const float*)d_in[7];
  float* out = (float*)d_out;

  unsigned short* qg  = (unsigned short*)d_ws;          // fp16 [B][N][D]
  unsigned short* kg  = qg + (size_t)BB * NN * DD;      // fp16 [B][N][D]
  unsigned short* vtg = kg + (size_t)BB * NN * DD;      // bf16 [B][D][N]

  proj_kernel<<<512, 256, 0, stream>>>(x, Wq, bq, Wk, bk, Wv, bv, qg, kg, vtg);
  attn_kernel<<<1024, 256, 65536, stream>>>(qg, kg, vtg, mask, out);
}

// Round 4
// 456.779 us; speedup vs baseline: 1.0474x; 1.0474x over previous
//
#include <hip/hip_runtime.h>
#include <cstdint>
#include <cstddef>

#define BB 64
#define NN 1024
#define DD 128

typedef short    bf16x8 __attribute__((ext_vector_type(8)));
typedef _Float16 f16x8  __attribute__((ext_vector_type(8)));
typedef float    f32x4  __attribute__((ext_vector_type(4)));

__device__ __forceinline__ unsigned short f2bf(float f) {
  union { float f; unsigned u; } v; v.f = f;
  unsigned r = v.u + 0x7FFFu + ((v.u >> 16) & 1u);
  return (unsigned short)(r >> 16);
}
__device__ __forceinline__ unsigned short f2h(float f) {
  union { _Float16 h; unsigned short u; } v; v.h = (_Float16)f;
  return v.u;
}
__device__ __forceinline__ float fast_tanh(float x) {
  x = fminf(15.0f, fmaxf(-15.0f, x));
  float e = __expf(2.0f * x);
  return (e - 1.0f) / (e + 1.0f);
}

// async global->LDS DMA, 16 B per lane (global_load_lds_dwordx4)
__device__ __forceinline__ void async_copy16(void* lptr, const void* gptr) {
  __builtin_amdgcn_global_load_lds(
      (const __attribute__((address_space(1))) unsigned int*)gptr,
      (__attribute__((address_space(3))) unsigned int*)lptr, 16, 0, 0);
}

// pack 16 mask ints (one 64-col tile slice for this lane) into 16 bits:
// bit (i*4 + {0,1,2,3}) = m[i].{x,y,z,w} & 1. Consumption at PV:
// bit (ks2*8+e) gates column j0 + ks2*32 + quad*8 + e.
__device__ __forceinline__ unsigned pack_mask(const int4 m[4]) {
  unsigned mb = 0;
#pragma unroll
  for (int i = 0; i < 4; ++i) {
    mb |= (unsigned)(m[i].x & 1) << (i * 4 + 0);
    mb |= (unsigned)(m[i].y & 1) << (i * 4 + 1);
    mb |= (unsigned)(m[i].z & 1) << (i * 4 + 2);
    mb |= (unsigned)(m[i].w & 1) << (i * 4 + 3);
  }
  return mb;
}

// ---------------------------------------------------------------------------
// Kernel 1: q = tanh(x@Wq^T+bq) (fp16), k = tanh(x@Wk^T+bk) (fp16),
//           vT = tanh(x@Wv^T+bv) transposed (bf16, [b][h][n]).  (unchanged)
// ---------------------------------------------------------------------------
__global__ __launch_bounds__(256, 2) void proj_kernel(
    const float* __restrict__ x,
    const float* __restrict__ Wq, const float* __restrict__ bq,
    const float* __restrict__ Wk, const float* __restrict__ bk,
    const float* __restrict__ Wv, const float* __restrict__ bv,
    unsigned short* __restrict__ qg,   // fp16 [B][N][D]
    unsigned short* __restrict__ kg,   // fp16 [B][N][D]
    unsigned short* __restrict__ vtg)  // bf16 [B][D][N]
{
  __shared__ unsigned short wlds[128 * 136];

  const int tid  = threadIdx.x;
  const int lane = tid & 63;
  const int wave = tid >> 6;
  const int quad = lane >> 4;
  const int mr   = lane & 15;
  const int m0   = blockIdx.x * 128;
  const int batch = m0 >> 10;
  const int n0    = m0 & 1023;

  bf16x8 xa[2][4];
#pragma unroll
  for (int mt = 0; mt < 2; ++mt) {
    const float* xr = x + (size_t)(m0 + wave * 32 + mt * 16 + mr) * DD + quad * 8;
#pragma unroll
    for (int ks = 0; ks < 4; ++ks) {
      const float4* xp = (const float4*)(xr + ks * 32);
      float4 f0 = xp[0], f1 = xp[1];
      bf16x8 f;
      f[0] = (short)f2bf(f0.x); f[1] = (short)f2bf(f0.y);
      f[2] = (short)f2bf(f0.z); f[3] = (short)f2bf(f0.w);
      f[4] = (short)f2bf(f1.x); f[5] = (short)f2bf(f1.y);
      f[6] = (short)f2bf(f1.z); f[7] = (short)f2bf(f1.w);
      xa[mt][ks] = f;
    }
  }

  const float* Wp[3] = {Wq, Wk, Wv};
  const float* bp[3] = {bq, bk, bv};

  for (int w = 0; w < 3; ++w) {
    __syncthreads();
    {
      const int row = tid >> 1, half = tid & 1;
      const float* src = Wp[w] + row * 128 + half * 64;
      unsigned short* dst = wlds + row * 136 + half * 64;
#pragma unroll
      for (int c = 0; c < 64; c += 8) {
        const float4* sp = (const float4*)(src + c);
        float4 f0 = sp[0], f1 = sp[1];
        unsigned short tmp[8];
        tmp[0] = f2bf(f0.x); tmp[1] = f2bf(f0.y); tmp[2] = f2bf(f0.z); tmp[3] = f2bf(f0.w);
        tmp[4] = f2bf(f1.x); tmp[5] = f2bf(f1.y); tmp[6] = f2bf(f1.z); tmp[7] = f2bf(f1.w);
        uint4 pk; __builtin_memcpy(&pk, tmp, 16);
        *(uint4*)(dst + c) = pk;
      }
    }
    __syncthreads();

    f32x4 z = {0.f, 0.f, 0.f, 0.f};
    f32x4 acc[2][8];
#pragma unroll
    for (int mt = 0; mt < 2; ++mt)
#pragma unroll
      for (int nt = 0; nt < 8; ++nt) acc[mt][nt] = z;

#pragma unroll
    for (int ks = 0; ks < 4; ++ks) {
#pragma unroll
      for (int nt = 0; nt < 8; ++nt) {
        bf16x8 bfr = *(const bf16x8*)(wlds + (nt * 16 + mr) * 136 + ks * 32 + quad * 8);
        acc[0][nt] = __builtin_amdgcn_mfma_f32_16x16x32_bf16(xa[0][ks], bfr, acc[0][nt], 0, 0, 0);
        acc[1][nt] = __builtin_amdgcn_mfma_f32_16x16x32_bf16(xa[1][ks], bfr, acc[1][nt], 0, 0, 0);
      }
    }

    if (w < 2) {
      unsigned short* outg = (w == 0) ? qg : kg;
#pragma unroll
      for (int mt = 0; mt < 2; ++mt) {
        const int rowbase = m0 + wave * 32 + mt * 16 + quad * 4;
#pragma unroll
        for (int nt = 0; nt < 8; ++nt) {
          float bb = bp[w][nt * 16 + mr];
#pragma unroll
          for (int r = 0; r < 4; ++r) {
            float t = fast_tanh(acc[mt][nt][r] + bb);
            outg[(size_t)(rowbase + r) * DD + nt * 16 + mr] = f2h(t);
          }
        }
      }
    } else {
      __syncthreads();
#pragma unroll
      for (int mt = 0; mt < 2; ++mt) {
        const int ib = wave * 32 + mt * 16 + quad * 4;
#pragma unroll
        for (int nt = 0; nt < 8; ++nt) {
          float bb = bp[2][nt * 16 + mr];
#pragma unroll
          for (int r = 0; r < 4; ++r) {
            float t = fast_tanh(acc[mt][nt][r] + bb);
            wlds[(nt * 16 + mr) * 136 + ib + r] = f2bf(t);
          }
        }
      }
      __syncthreads();
      const int h = tid >> 1, half = tid & 1;
      const unsigned short* src = wlds + h * 136 + half * 64;
      unsigned short* dst = vtg + (size_t)(batch * 128 + h) * NN + n0 + half * 64;
#pragma unroll
      for (int c = 0; c < 64; c += 8)
        *(uint4*)(dst + c) = *(const uint4*)(src + c);
    }
  }
}

// ---------------------------------------------------------------------------
// Kernel 2: flash-style masked attention, R4.
// Block = 512 threads (8 waves x 16 rows = 128 q-rows), j-tiles of 64.
// Sync semantics = R1's PROVEN structure (full __syncthreads drain after DMA
// issue; no counted vmcnt waits -- R3's split drain produced NaN).
// Structural wins kept from the R3 theory:
//  - 128 rows/block: one K/V staging round serves 2x the q-rows -> exposed
//    drain events per CU HALVED (2 blocks x 16 tiles vs 4 x 16 in R1).
//  - plds separate region (no klds alias) -> post-S barrier gone.
//    2 barriers/tile total (R1: 3, R0: 4):
//      B1 loop-top: prev tile's S/PV LDS reads done before restage
//      B2 post-issue __syncthreads: full drain, K+V visible
//  - mask prefetch issued AFTER B2 (never extends the drain), consumed at
//    bottom pack with a full S+PV window to land.
//  - rowsum via MFMA vs ones-B-frag (validated in R2): rs=mfma(pm,ones,rs),
//    D rows (quad*4+r, col=mr) match o[nt][r] -> no shuffles.
// LDS: K [64][128] f16 swz 16K | VT [128][64] bf16 swz 16K | P [128][72] 18K
//   = 51200 B -> 2 blocks/CU, 16 waves/CU. Grid 512 fully co-resident.
// XCD: all 8 i-blocks of batch b land on XCD b&7 (K/V 512 KB/batch in L2).
// ---------------------------------------------------------------------------
__global__ __launch_bounds__(512, 4) void attn_kernel(
    const unsigned short* __restrict__ qg,
    const unsigned short* __restrict__ kg,
    const unsigned short* __restrict__ vtg,
    const int* __restrict__ mask,
    float* __restrict__ out)
{
  extern __shared__ unsigned short lds[];
  unsigned short* klds = lds;            // [64][128] f16 swizzled
  unsigned short* vlds = lds + 8192;     // [128][64] bf16 swizzled
  unsigned short* plds = lds + 16384;    // [128][72] bf16 padded

  const int tid  = threadIdx.x;
  const int lane = tid & 63;
  const int wave = tid >> 6;             // 0..7
  const int quad = lane >> 4;
  const int mr   = lane & 15;

  const int bx    = blockIdx.x;          // 512 blocks
  const int batch = ((bx >> 6) << 3) | (bx & 7);   // same-batch -> same XCD
  const int i0    = ((bx >> 3) & 7) * 128;

  const unsigned short* kgb = kg  + (size_t)batch * NN * DD;
  const unsigned short* vtb = vtg + (size_t)batch * DD * NN;
  const int* mrow = mask + ((size_t)batch << 20) + (size_t)(i0 + wave * 16 + mr) * NN;

  // Q A-frags (fp16): row = i0 + wave*16 + mr, k = ks*32 + quad*8 + e
  f16x8 qa[4];
#pragma unroll
  for (int ks = 0; ks < 4; ++ks)
    qa[ks] = *(const f16x8*)(qg +
        ((size_t)batch * NN + i0 + wave * 16 + mr) * DD + ks * 32 + quad * 8);

  f32x4 z = {0.f, 0.f, 0.f, 0.f};
  f32x4 o[8];
#pragma unroll
  for (int nt = 0; nt < 8; ++nt) o[nt] = z;
  f32x4 rs = z;                       // rowsum accumulator (MFMA vs ones)
  bf16x8 ones;
#pragma unroll
  for (int e = 0; e < 8; ++e) ones[e] = (short)0x3F80;  // bf16 1.0

  // mask tile 0: load + pack before the loop
  unsigned mb;
  {
    int4 m0r[4];
    m0r[0] = *(const int4*)(mrow + quad * 8);
    m0r[1] = *(const int4*)(mrow + quad * 8 + 4);
    m0r[2] = *(const int4*)(mrow + 32 + quad * 8);
    m0r[3] = *(const int4*)(mrow + 32 + quad * 8 + 4);
    mb = pack_mask(m0r);
  }

  for (int t = 0; t < 16; ++t) {
    const int j0 = t * 64;

    __syncthreads();  // B1: all waves done with tile t-1's klds/vlds/plds
                      // reads (vmcnt already 0: bottom pack drained it)

    // issue staging for tile t (16B/lane; dest contiguous per wave)
#pragma unroll
    for (int p = 0; p < 2; ++p) {
      int s = p * 512 + tid;
      int kr = s >> 4, kgp = (s & 15) ^ (kr & 15);
      async_copy16(klds + s * 8, kgb + (size_t)(j0 + kr) * DD + kgp * 8);
    }
#pragma unroll
    for (int p = 0; p < 2; ++p) {
      int s = p * 512 + tid;
      int vr = s >> 3, vgp = (s & 7) ^ (vr & 7);
      async_copy16(vlds + s * 8, vtb + (size_t)vr * NN + j0 + vgp * 8);
    }

    __syncthreads();  // B2: full drain (vmcnt(0)) + barrier -> K+V visible.
                      // Only staging is outstanding here, so the drain waits
                      // exactly the 4 DMAs.

    // mask loads for tile t+1: issued after B2 so they never extend the
    // drain; consumed at bottom pack with a full S+PV window to land.
    int4 mreg[4];
    {
      const int j0n = ((t + 1) & 15) * 64;
      mreg[0] = *(const int4*)(mrow + j0n + quad * 8);
      mreg[1] = *(const int4*)(mrow + j0n + quad * 8 + 4);
      mreg[2] = *(const int4*)(mrow + j0n + 32 + quad * 8);
      mreg[3] = *(const int4*)(mrow + j0n + 32 + quad * 8 + 4);
    }

    // S = Q @ K^T (fp16 MFMA); per-wave tile 16 x 64; swizzled klds reads
    f32x4 s[4];
#pragma unroll
    for (int nt = 0; nt < 4; ++nt) s[nt] = z;
    __builtin_amdgcn_s_setprio(1);
#pragma unroll
    for (int ks = 0; ks < 4; ++ks) {
#pragma unroll
      for (int nt = 0; nt < 4; ++nt) {
        f16x8 kb = *(const f16x8*)(klds + (nt * 16 + mr) * 128 + (((ks * 4 + quad) ^ mr) * 8));
        s[nt] = __builtin_amdgcn_mfma_f32_16x16x32_f16(qa[ks], kb, s[nt], 0, 0, 0);
      }
    }
    __builtin_amdgcn_s_setprio(0);

    // P = exp(S) -> bf16 -> plds. Wave-private rows (write wave*16+quad*4+r,
    // read wave*16+mr): no barrier; same-wave ds ordering via lgkmcnt.
#pragma unroll
    for (int nt = 0; nt < 4; ++nt) {
#pragma unroll
      for (int r = 0; r < 4; ++r)
        plds[(wave * 16 + quad * 4 + r) * 72 + nt * 16 + mr] = f2bf(__expf(s[nt][r]));
    }

    // O += P_masked @ V; rowsum via MFMA against ones-B-frag.
    // vlds was drained at B2; plds is wave-private.
#pragma unroll
    for (int ks2 = 0; ks2 < 2; ++ks2) {
      bf16x8 pa = *(const bf16x8*)(plds + (wave * 16 + mr) * 72 + ks2 * 32 + quad * 8);
      bf16x8 pm;
#pragma unroll
      for (int e = 0; e < 8; ++e) {
        unsigned bit = (mb >> (ks2 * 8 + e)) & 1u;
        pm[e] = bit ? pa[e] : (short)0;
      }
      rs = __builtin_amdgcn_mfma_f32_16x16x32_bf16(pm, ones, rs, 0, 0, 0);
      __builtin_amdgcn_s_setprio(1);
#pragma unroll
      for (int nt = 0; nt < 8; ++nt) {
        bf16x8 vb = *(const bf16x8*)(vlds + (nt * 16 + mr) * 64 +
                                     (((ks2 * 4 + quad) ^ (mr & 7)) * 8));
        o[nt] = __builtin_amdgcn_mfma_f32_16x16x32_bf16(pm, vb, o[nt], 0, 0, 0);
      }
      __builtin_amdgcn_s_setprio(0);
    }

    // pack tile t+1's mask; the wait here drains M (had S+PV to land)
    mb = pack_mask(mreg);
  }

  // rs[r] = masked rowsum for row wave*16+quad*4+r -- same lane map as o[nt][r]
  float* ob = out + ((size_t)batch * NN + i0) * DD;
#pragma unroll
  for (int r = 0; r < 4; ++r) {
    float inv = 1.0f / rs[r];
    float* orow = ob + (size_t)(wave * 16 + quad * 4 + r) * DD + mr;
#pragma unroll
    for (int nt = 0; nt < 8; ++nt)
      orow[nt * 16] = o[nt][r] * inv;
  }
}

// ---------------------------------------------------------------------------
extern "C" void kernel_launch(void* const* d_in, const int* in_sizes, int n_in,
                              void* d_out, int out_size, void* d_ws, size_t ws_size,
                              hipStream_t stream) {
  (void)in_sizes; (void)n_in; (void)out_size; (void)ws_size;
  const float* x  = (const float*)d_in[0];
  const int* mask = (const int*)d_in[1];
  const float* Wv = (const float*)d_in[2];
  const float* bv = (const float*)d_in[3];
  const float* Wk = (const float*)d_in[4];
  const float* bk = (const float*)d_in[5];
  const float* Wq = (const float*)d_in[6];
  const float* bq = (const float*)d_in[7];
  float* out = (float*)d_out;

  unsigned short* qg  = (unsigned short*)d_ws;          // fp16 [B][N][D]
  unsigned short* kg  = qg + (size_t)BB * NN * DD;      // fp16 [B][N][D]
  unsigned short* vtg = kg + (size_t)BB * NN * DD;      // bf16 [B][D][N]

  proj_kernel<<<512, 256, 0, stream>>>(x, Wq, bq, Wk, bk, Wv, bv, qg, kg, vtg);
  attn_kernel<<<512, 512, 51200, stream>>>(qg, kg, vtg, mask, out);
}